// Round 2
// baseline (691.697 us; speedup 1.0000x reference)
//
#include <hip/hip_runtime.h>

#define T_STEPS 512
#define F_IN    64
#define HID     20
#define G4      80     // 4*HID gates per batch element
#define BT      2      // batch tile per block
#define NTH     160    // BT*G4 threads
#define NCLS    10

__device__ __forceinline__ float sigf(float x) {
    return __builtin_amdgcn_rcpf(1.0f + __expf(-x));
}
__device__ __forceinline__ float tanh_fast(float x) {
    float e = __expf(2.0f * x);
    return 1.0f - 2.0f * __builtin_amdgcn_rcpf(e + 1.0f);
}
__device__ __forceinline__ float4 fma4(float4 a, float4 b, float4 c) {
    return make_float4(fmaf(a.x, b.x, c.x), fmaf(a.y, b.y, c.y),
                       fmaf(a.z, b.z, c.z), fmaf(a.w, b.w, c.w));
}
__device__ __forceinline__ float4 add4(float4 a, float4 b) {
    return make_float4(a.x + b.x, a.y + b.y, a.z + b.z, a.w + b.w);
}

extern "C" __global__ __launch_bounds__(NTH, 2)
void lstm_fused(const float* __restrict__ x,
                const float* __restrict__ W_ih0, const float* __restrict__ W_hh0,
                const float* __restrict__ b0,
                const float* __restrict__ W_ih1, const float* __restrict__ W_hh1,
                const float* __restrict__ b1,
                const float* __restrict__ W_fc, const float* __restrict__ b_fc,
                float* __restrict__ out)
{
    __shared__ float xs[2][BT * F_IN];   // double-buffered x_t
    __shared__ float gs0[BT * G4];       // layer0 gates, layout [b][h][gate]
    __shared__ float gs1[BT * G4];       // layer1 gates
    __shared__ float h0s[BT * HID];
    __shared__ float h1s[BT * HID];

    const int tid = threadIdx.x;
    const int bg  = blockIdx.x;              // 0..511, batch base = bg*BT
    const int b   = tid / G4;                // 0..1
    const int g   = tid - b * G4;            // 0..79 (i,f,g,o blocks of 20)
    const int gq  = g / HID;                 // gate type 0..3
    const int gh  = g - gq * HID;            // h index 0..19
    const int gidx = b * G4 + gh * 4 + gq;   // [b][h][gate] slot
    const bool isG = (gq == 2);

    // ---- per-thread weight columns in registers ----
    float4 wx4[16], wh04[5], wi14[5], wh14[5];
    {
        const float4* p = (const float4*)(W_ih0 + g * F_IN);
        #pragma unroll
        for (int k = 0; k < 16; ++k) wx4[k] = p[k];
        const float4* p2 = (const float4*)(W_hh0 + g * HID);
        #pragma unroll
        for (int k = 0; k < 5; ++k) wh04[k] = p2[k];
        const float4* p3 = (const float4*)(W_ih1 + g * HID);
        #pragma unroll
        for (int k = 0; k < 5; ++k) wi14[k] = p3[k];
        const float4* p4 = (const float4*)(W_hh1 + g * HID);
        #pragma unroll
        for (int k = 0; k < 5; ++k) wh14[k] = p4[k];
    }
    const float bias0 = b0[g];
    const float bias1 = b1[g];

    // state-update threads: tid < 40 -> (b,h), gs slot = 4*tid (see layout)
    float c0 = 0.f, c1 = 0.f;

    // FC threads: tid in [40,60): 2 batch x 10 classes, pipelined 1 step behind
    const int ft  = tid - 40;
    const int fb  = ft / NCLS;
    const int fcc = ft - fb * NCLS;
    const bool isFC = (tid >= 40 && tid < 60);
    const float* wfp = W_fc + (size_t)fcc * (T_STEPS * HID);
    float4 wf[5];
    float facc = 0.f;

    // x staging threads: tid < 128 own one (b,f) element per step
    const int xb = tid >> 6;
    const int xf = tid & 63;
    const float* xptr = x + ((size_t)(bg * BT + xb) * T_STEPS) * F_IN + xf;

    float xreg = 0.f;
    if (tid < 128) {
        xs[0][tid] = xptr[0];        // x(0)
        xreg = xptr[F_IN];           // x(1)
    }
    if (tid < BT * HID) { h0s[tid] = 0.f; h1s[tid] = 0.f; }
    __syncthreads();

    for (int t = 0; t < T_STEPS; ++t) {
        // ---------- P1: stage x(t+1); layer0 gates from xs[t&1], h0s ----------
        if (tid < 128) xs[(t + 1) & 1][tid] = xreg;
        {
            const float4* xr = (const float4*)(xs[t & 1] + b * F_IN);
            const float4* hr = (const float4*)(h0s + b * HID);
            float4 A0 = make_float4(0,0,0,0), A1 = A0, A2 = A0, A3 = A0;
            #pragma unroll
            for (int k = 0; k < 4; ++k) {
                A0 = fma4(xr[4*k+0], wx4[4*k+0], A0);
                A1 = fma4(xr[4*k+1], wx4[4*k+1], A1);
                A2 = fma4(xr[4*k+2], wx4[4*k+2], A2);
                A3 = fma4(xr[4*k+3], wx4[4*k+3], A3);
            }
            A0 = fma4(hr[0], wh04[0], A0);
            A1 = fma4(hr[1], wh04[1], A1);
            A2 = fma4(hr[2], wh04[2], A2);
            A3 = fma4(hr[3], wh04[3], A3);
            A0 = fma4(hr[4], wh04[4], A0);
            float4 S = add4(add4(A0, A2), add4(A1, A3));
            float acc = bias0 + ((S.x + S.y) + (S.z + S.w));
            gs0[gidx] = isG ? tanh_fast(acc) : sigf(acc);
        }
        __syncthreads();                                   // A: gates0 ready

        // ---------- P2: update h0/c0 | FC accum for t-1 | prefetches ----------
        if (tid < BT * HID) {
            float4 gv = *(const float4*)(gs0 + 4 * tid);   // i,f,g,o of (b,h)
            c0 = fmaf(gv.y, c0, gv.x * gv.z);
            h0s[tid] = gv.w * tanh_fast(c0);
        }
        if (isFC) {
            if (t > 0) {
                const float4* hr1 = (const float4*)(h1s + fb * HID);
                float4 F0 = make_float4(0,0,0,0), F1 = F0;
                F0 = fma4(hr1[0], wf[0], F0);
                F1 = fma4(hr1[1], wf[1], F1);
                F0 = fma4(hr1[2], wf[2], F0);
                F1 = fma4(hr1[3], wf[3], F1);
                F0 = fma4(hr1[4], wf[4], F0);
                float4 FS = add4(F0, F1);
                facc += (FS.x + FS.y) + (FS.z + FS.w);
            }
            const float4* wp = (const float4*)(wfp + t * HID);
            #pragma unroll
            for (int k = 0; k < 5; ++k) wf[k] = wp[k];     // W_fc row t (used at t+1)
        }
        if (tid < 128 && t + 2 < T_STEPS) xreg = xptr[(size_t)(t + 2) * F_IN];
        __syncthreads();                                   // B: h0 updated

        // ---------- P3: layer1 gates from h0s(t), h1s(t-1) ----------
        {
            const float4* h0r = (const float4*)(h0s + b * HID);
            const float4* h1r = (const float4*)(h1s + b * HID);
            float4 B0 = make_float4(0,0,0,0), B1 = B0, B2 = B0, B3 = B0;
            B0 = fma4(h0r[0], wi14[0], B0);
            B1 = fma4(h0r[1], wi14[1], B1);
            B2 = fma4(h0r[2], wi14[2], B2);
            B3 = fma4(h0r[3], wi14[3], B3);
            B0 = fma4(h0r[4], wi14[4], B0);
            B1 = fma4(h1r[0], wh14[0], B1);
            B2 = fma4(h1r[1], wh14[1], B2);
            B3 = fma4(h1r[2], wh14[2], B3);
            B0 = fma4(h1r[3], wh14[3], B0);
            B1 = fma4(h1r[4], wh14[4], B1);
            float4 S1 = add4(add4(B0, B2), add4(B1, B3));
            float acc1 = bias1 + ((S1.x + S1.y) + (S1.z + S1.w));
            gs1[gidx] = isG ? tanh_fast(acc1) : sigf(acc1);
        }
        __syncthreads();                                   // C: gates1 ready

        // ---------- P4: update h1/c1 ----------
        if (tid < BT * HID) {
            float4 gv = *(const float4*)(gs1 + 4 * tid);
            c1 = fmaf(gv.y, c1, gv.x * gv.z);
            h1s[tid] = gv.w * tanh_fast(c1);
        }
        // no barrier: gs0 rewrite (P1 t+1) races with nothing (gs1 separate,
        // h1s readers are post-barrier-A/B next step)
    }

    __syncthreads();
    // epilogue: FC accum for t = T-1, then store
    if (isFC) {
        const float4* hr1 = (const float4*)(h1s + fb * HID);
        float4 F0 = make_float4(0,0,0,0), F1 = F0;
        F0 = fma4(hr1[0], wf[0], F0);
        F1 = fma4(hr1[1], wf[1], F1);
        F0 = fma4(hr1[2], wf[2], F0);
        F1 = fma4(hr1[3], wf[3], F1);
        F0 = fma4(hr1[4], wf[4], F0);
        float4 FS = add4(F0, F1);
        facc += (FS.x + FS.y) + (FS.z + FS.w);
        out[(size_t)(bg * BT + fb) * NCLS + fcc] = facc + b_fc[fcc];
    }
}

extern "C" void kernel_launch(void* const* d_in, const int* in_sizes, int n_in,
                              void* d_out, int out_size, void* d_ws, size_t ws_size,
                              hipStream_t stream) {
    const float* x     = (const float*)d_in[0];
    const float* W_ih0 = (const float*)d_in[1];
    const float* W_hh0 = (const float*)d_in[2];
    const float* b0    = (const float*)d_in[3];
    const float* W_ih1 = (const float*)d_in[4];
    const float* W_hh1 = (const float*)d_in[5];
    const float* b1    = (const float*)d_in[6];
    const float* W_fc  = (const float*)d_in[7];
    const float* b_fc  = (const float*)d_in[8];
    float* out = (float*)d_out;

    lstm_fused<<<dim3(512), dim3(NTH), 0, stream>>>(
        x, W_ih0, W_hh0, b0, W_ih1, W_hh1, b1, W_fc, b_fc, out);
}

// Round 3
// 673.876 us; speedup vs baseline: 1.0264x; 1.0264x over previous
//
#include <hip/hip_runtime.h>

#define T_STEPS 512
#define F_IN    64
#define HID     20
#define NCLS    10
#define BATCH   1024

// ---------------- helpers ----------------
__device__ __forceinline__ float sigf(float x) {
    return __builtin_amdgcn_rcpf(1.0f + __expf(-x));
}
__device__ __forceinline__ float tanh_fast(float x) {
    float e = __expf(2.0f * x);
    return 1.0f - 2.0f * __builtin_amdgcn_rcpf(e + 1.0f);
}
// unified gate activation: sigmoid(x) or tanh(x) = 2*sigmoid(2x)-1 (one exp+rcp)
__device__ __forceinline__ float actf(float x, bool isG) {
    float y = isG ? 2.0f * x : x;
    float r = __builtin_amdgcn_rcpf(1.0f + __expf(-y));
    return isG ? 2.0f * r - 1.0f : r;
}
__device__ __forceinline__ float bcast(float v, int lane) {
    return __int_as_float(__builtin_amdgcn_readlane(__float_as_int(v), lane));
}

// ---------------- kernel A: Z0[B*T][80] = x @ W_ih0^T + b0 ----------------
// thread = one row of x; weights are wave-uniform -> scalar loads (SGPR operand FMAs)
extern "C" __global__ __launch_bounds__(256)
void zgemm(const float* __restrict__ x, const float* __restrict__ W,
           const float* __restrict__ b0, float* __restrict__ Z)
{
    const size_t row = (size_t)blockIdx.x * 256 + threadIdx.x;  // grid covers B*T rows
    float xr[F_IN];
    const float4* xp = (const float4*)(x + row * F_IN);
    #pragma unroll
    for (int k = 0; k < F_IN / 4; ++k) ((float4*)xr)[k] = xp[k];

    float* zr = Z + row * 80;
    #pragma unroll 1
    for (int c = 0; c < 80; c += 4) {
        float a0 = b0[c], a1 = b0[c + 1], a2 = b0[c + 2], a3 = b0[c + 3];
        const float* w0 = W + c * F_IN;       // uniform address -> s_load
        #pragma unroll
        for (int k = 0; k < F_IN; ++k) {
            a0 = fmaf(w0[k],           xr[k], a0);
            a1 = fmaf(w0[F_IN + k],    xr[k], a1);
            a2 = fmaf(w0[2*F_IN + k],  xr[k], a2);
            a3 = fmaf(w0[3*F_IN + k],  xr[k], a3);
        }
        float4 v = make_float4(a0, a1, a2, a3);
        *(float4*)(zr + c) = v;
    }
}

// ---------------- kernel B: barrier-free recurrence, 1 wave / batch elem ----------------
// lane l: primary gate g1=l (0..63); lanes 0..15 also secondary gate g2=64+l.
// gate order i[0..19] f[20..39] g[40..59] o[60..79].
// h broadcast via readlane -> uniform (SGPR) operands; update gather via __shfl.
extern "C" __global__ __launch_bounds__(64)
void lstm_rec(const float* __restrict__ Z0,
              const float* __restrict__ W_hh0,
              const float* __restrict__ W_ih1, const float* __restrict__ W_hh1,
              const float* __restrict__ b1,
              const float* __restrict__ W_fc, const float* __restrict__ b_fc,
              float* __restrict__ out)
{
    const int b = blockIdx.x;
    const int l = threadIdx.x;
    const int g1 = l;
    const int g2 = 64 + (l & 15);
    const bool isG = (l >= 40 && l < 60);   // primary cell-gate lanes

    // per-lane weight rows (registers)
    float wh0p[HID], wh0s[HID], wi1p[HID], wi1s[HID], wh1p[HID], wh1s[HID];
    {
        const float4* p;
        p = (const float4*)(W_hh0 + g1 * HID);
        #pragma unroll
        for (int k = 0; k < 5; ++k) ((float4*)wh0p)[k] = p[k];
        p = (const float4*)(W_hh0 + g2 * HID);
        #pragma unroll
        for (int k = 0; k < 5; ++k) ((float4*)wh0s)[k] = p[k];
        p = (const float4*)(W_ih1 + g1 * HID);
        #pragma unroll
        for (int k = 0; k < 5; ++k) ((float4*)wi1p)[k] = p[k];
        p = (const float4*)(W_ih1 + g2 * HID);
        #pragma unroll
        for (int k = 0; k < 5; ++k) ((float4*)wi1s)[k] = p[k];
        p = (const float4*)(W_hh1 + g1 * HID);
        #pragma unroll
        for (int k = 0; k < 5; ++k) ((float4*)wh1p)[k] = p[k];
        p = (const float4*)(W_hh1 + g2 * HID);
        #pragma unroll
        for (int k = 0; k < 5; ++k) ((float4*)wh1s)[k] = p[k];
    }
    const float b1p = b1[g1];
    const float b1s = b1[g2];

    const int cls = (l < NCLS) ? l : 0;
    const float* wfp = W_fc + (size_t)cls * (T_STEPS * HID);

    float c0 = 0.f, c1 = 0.f, h0v = 0.f, h1v = 0.f, facc = 0.f;
    float sh0[HID], sh1[HID];
    #pragma unroll
    for (int j = 0; j < HID; ++j) { sh0[j] = 0.f; sh1[j] = 0.f; }

    const float* zrow = Z0 + (size_t)b * T_STEPS * 80;
    // 2-deep Z prefetch
    float zp0 = zrow[l],        zs0 = zrow[g2];
    float zp1 = zrow[80 + l],   zs1 = zrow[80 + g2];

    for (int t = 0; t < T_STEPS; ++t) {
        // W_fc row for this t (consumed at step end ~500 cycles later)
        float4 wf[5];
        {
            const float4* p = (const float4*)(wfp + t * HID);
            #pragma unroll
            for (int k = 0; k < 5; ++k) wf[k] = p[k];
        }
        // rotate Z prefetch, issue t+2
        const float zp = zp0, zs = zs0;
        zp0 = zp1; zs0 = zs1;
        if (t + 2 < T_STEPS) {
            const float* zr2 = zrow + (size_t)(t + 2) * 80;
            zp1 = zr2[l];
            zs1 = zr2[g2];
        }

        // ---- layer0 gates: z + W_hh0 @ h0 ----
        float a_p = zp, a_s = zs;
        #pragma unroll
        for (int j = 0; j < HID; ++j) {
            a_p = fmaf(sh0[j], wh0p[j], a_p);
            a_s = fmaf(sh0[j], wh0s[j], a_s);
        }
        const float actP = actf(a_p, isG);
        const float actS = sigf(a_s);          // secondary gates are all o -> sigmoid

        // ---- layer1 h1-part (independent of h0 update -> overlaps) ----
        float bp_ = b1p, bs_ = b1s;
        #pragma unroll
        for (int j = 0; j < HID; ++j) {
            bp_ = fmaf(sh1[j], wh1p[j], bp_);
            bs_ = fmaf(sh1[j], wh1s[j], bs_);
        }

        // ---- layer0 state update (meaningful on lanes 0..19) ----
        {
            float fv = __shfl(actP, l + 20);
            float gv = __shfl(actP, l + 40);
            float oA = __shfl(actP, l + 60);
            float oB = __shfl(actS, l - 4);
            float ov = (l < 4) ? oA : oB;
            c0 = fmaf(fv, c0, actP * gv);      // actP = i[l] on lanes <20
            h0v = ov * tanh_fast(c0);
        }
        // broadcast h0 -> uniform
        #pragma unroll
        for (int j = 0; j < HID; ++j) sh0[j] = bcast(h0v, j);

        // ---- layer1 h0-part + activation ----
        #pragma unroll
        for (int j = 0; j < HID; ++j) {
            bp_ = fmaf(sh0[j], wi1p[j], bp_);
            bs_ = fmaf(sh0[j], wi1s[j], bs_);
        }
        const float actP1 = actf(bp_, isG);
        const float actS1 = sigf(bs_);

        // ---- layer1 state update ----
        {
            float fv = __shfl(actP1, l + 20);
            float gv = __shfl(actP1, l + 40);
            float oA = __shfl(actP1, l + 60);
            float oB = __shfl(actS1, l - 4);
            float ov = (l < 4) ? oA : oB;
            c1 = fmaf(fv, c1, actP1 * gv);
            h1v = ov * tanh_fast(c1);
        }
        // broadcast h1 -> uniform
        #pragma unroll
        for (int j = 0; j < HID; ++j) sh1[j] = bcast(h1v, j);

        // ---- FC accumulation for this t (lanes 0..9 meaningful) ----
        {
            const float* wfs = (const float*)wf;
            #pragma unroll
            for (int j = 0; j < HID; ++j) facc = fmaf(sh1[j], wfs[j], facc);
        }
    }

    if (l < NCLS) out[(size_t)b * NCLS + l] = facc + b_fc[l];
}

extern "C" void kernel_launch(void* const* d_in, const int* in_sizes, int n_in,
                              void* d_out, int out_size, void* d_ws, size_t ws_size,
                              hipStream_t stream) {
    const float* x     = (const float*)d_in[0];
    const float* W_ih0 = (const float*)d_in[1];
    const float* W_hh0 = (const float*)d_in[2];
    const float* b0    = (const float*)d_in[3];
    const float* W_ih1 = (const float*)d_in[4];
    const float* W_hh1 = (const float*)d_in[5];
    const float* b1    = (const float*)d_in[6];
    const float* W_fc  = (const float*)d_in[7];
    const float* b_fc  = (const float*)d_in[8];
    float* out = (float*)d_out;

    float* Z0 = (float*)d_ws;   // needs B*T*80*4 = 167.8 MB of workspace

    const int rows = BATCH * T_STEPS;                 // 524288
    zgemm<<<dim3(rows / 256), dim3(256), 0, stream>>>(x, W_ih0, b0, Z0);
    lstm_rec<<<dim3(BATCH), dim3(64), 0, stream>>>(Z0, W_hh0, W_ih1, W_hh1,
                                                   b1, W_fc, b_fc, out);
}